// Round 5
// baseline (55.351 us; speedup 1.0000x reference)
//
#include <hip/hip_runtime.h>
#include <hip/hip_bf16.h>

// Spherical harmonics Y_lm, l=0..3, per point of X[8,512,512,3] (fp32).
// Output per point: 16 rows (l,m ascending) x 2 (re,im) = 32 floats = 8 float4.
// Persistent grid (2048 blocks, grid-stride over point batches). Per batch:
// per-wave register->LDS (XOR-swizzled) transpose, wave-level lgkmcnt sync
// (no block barrier), nontemporal fully-coalesced dwordx4 stores.

typedef float f32x4 __attribute__((ext_vector_type(4)));

__global__ __launch_bounds__(256) void spharm_kernel(
    const float* __restrict__ X, float* __restrict__ out, int n, int iters)
{
    __shared__ f32x4 lds[4 * 512];  // 4 waves x 64 points x 8 float4 = 32 KB
    const int lane = threadIdx.x & 63;
    const int wave = threadIdx.x >> 6;
    f32x4* w = &lds[wave * 512];
    f32x4* of4 = reinterpret_cast<f32x4*>(out);

    for (int it = 0; it < iters; ++it) {
        const int pb = (it * gridDim.x + blockIdx.x) * 256;  // block base point
        const int p = pb + threadIdx.x;

        f32x4 v[8];
        if (p < n) {
            const float x = X[3 * p + 0];
            const float y = X[3 * p + 1];
            const float z = X[3 * p + 2];

            const float r  = sqrtf(x * x + y * y + z * z);
            const float ct = z / (r + 1e-12f);
            float st2 = 1.0f - ct * ct;
            st2 = st2 < 0.0f ? 0.0f : (st2 > 1.0f ? 1.0f : st2);
            const float st = sqrtf(st2);

            // cos(phi), sin(phi); atan2(0,0)=0 -> (c,s)=(1,0)
            const float rxy2 = x * x + y * y;
            float c1, s1;
            if (rxy2 > 0.0f) {
                const float inv = rsqrtf(rxy2);
                c1 = x * inv;
                s1 = y * inv;
            } else {
                c1 = 1.0f;
                s1 = 0.0f;
            }
            const float c2 = c1 * c1 - s1 * s1;
            const float s2 = 2.0f * c1 * s1;
            const float c3 = c2 * c1 - s2 * s1;
            const float s3 = s2 * c1 + c2 * s1;

            // Associated Legendre (Condon-Shortley phase)
            const float P10 = ct;
            const float P11 = -st;
            const float P20 = 0.5f * (3.0f * ct * ct - 1.0f);
            const float P21 = -3.0f * ct * st;
            const float P22 = 3.0f * st2;
            const float P30 = 0.5f * ct * (5.0f * ct * ct - 3.0f);
            const float P31 = -1.5f * st * (5.0f * ct * ct - 1.0f);
            const float P32 = 15.0f * ct * st2;
            const float P33 = -15.0f * st * st2;

            const float N00 = 0.28209479177387814f;
            const float N10 = 0.48860251190291990f;
            const float N11 = 0.34549414947133550f;
            const float N20 = 0.63078313050504010f;
            const float N21 = 0.25751613468212640f;
            const float N22 = 0.12875806734106327f;
            const float N30 = 0.74635266518023080f;
            const float N31 = 0.21545345607610050f;
            const float N32 = 0.06813236509555433f;
            const float N33 = 0.02781492157551894f;

            const float q11 = N11 * P11;
            const float q21 = N21 * P21;
            const float q22 = N22 * P22;
            const float q31 = N31 * P31;
            const float q32 = N32 * P32;
            const float q33 = N33 * P33;

            const float re11 = q11 * c1, im11 = q11 * s1;
            const float re21 = q21 * c1, im21 = q21 * s1;
            const float re22 = q22 * c2, im22 = q22 * s2;
            const float re31 = q31 * c1, im31 = q31 * s1;
            const float re32 = q32 * c2, im32 = q32 * s2;
            const float re33 = q33 * c3, im33 = q33 * s3;

            v[0] = (f32x4){N00, 0.0f, -re11, im11};          // l0m0 | l1m-1
            v[1] = (f32x4){N10 * P10, 0.0f, re11, im11};     // l1m0 | l1m1
            v[2] = (f32x4){re22, -im22, -re21, im21};        // l2m-2 | l2m-1
            v[3] = (f32x4){N20 * P20, 0.0f, re21, im21};     // l2m0 | l2m1
            v[4] = (f32x4){re22, im22, -re33, im33};         // l2m2 | l3m-3
            v[5] = (f32x4){re32, -im32, -re31, im31};        // l3m-2 | l3m-1
            v[6] = (f32x4){N30 * P30, 0.0f, re31, im31};     // l3m0 | l3m1
            v[7] = (f32x4){re32, im32, re33, im33};          // l3m2 | l3m3
        } else {
            #pragma unroll
            for (int j = 0; j < 8; ++j) v[j] = (f32x4){0.f, 0.f, 0.f, 0.f};
        }

        // WAR guard vs previous iteration's ds_reads (wave-local; DS pipe is
        // in-order per wave, this is belt-and-braces and nearly free).
        asm volatile("s_waitcnt lgkmcnt(0)" ::: "memory");

        // Per-wave LDS transpose, XOR-swizzled: conflict-free write and read.
        #pragma unroll
        for (int j = 0; j < 8; ++j)
            w[lane * 8 + (j ^ (lane & 7))] = v[j];

        // No cross-wave sharing: wave-level LDS drain instead of barrier.
        asm volatile("s_waitcnt lgkmcnt(0)" ::: "memory");

        const size_t base_f4 = (size_t)pb * 8 + (size_t)wave * 512;
        const bool full = (pb + 256) <= n;

        if (full) {
            #pragma unroll
            for (int j = 0; j < 8; ++j) {
                const int q = j * 64 + lane;
                const int pw = q >> 3;
                const int s = q & 7;
                const f32x4 val = w[pw * 8 + (s ^ (pw & 7))];
                __builtin_nontemporal_store(val, &of4[base_f4 + q]);
            }
        } else {
            const size_t lim_f4 = (size_t)n * 8;
            #pragma unroll
            for (int j = 0; j < 8; ++j) {
                const int q = j * 64 + lane;
                const int pw = q >> 3;
                const int s = q & 7;
                const f32x4 val = w[pw * 8 + (s ^ (pw & 7))];
                if (base_f4 + q < lim_f4)
                    __builtin_nontemporal_store(val, &of4[base_f4 + q]);
            }
        }
    }
}

extern "C" void kernel_launch(void* const* d_in, const int* in_sizes, int n_in,
                              void* d_out, int out_size, void* d_ws, size_t ws_size,
                              hipStream_t stream) {
    const float* X = (const float*)d_in[0];
    float* out = (float*)d_out;
    const int n = in_sizes[0] / 3;  // number of points
    const int total_blocks = (n + 255) / 256;
    const int blocks = total_blocks < 2048 ? total_blocks : 2048;
    const int iters = (total_blocks + blocks - 1) / blocks;
    spharm_kernel<<<blocks, 256, 0, stream>>>(X, out, n, iters);
}

// Round 6
// 54.398 us; speedup vs baseline: 1.0175x; 1.0175x over previous
//
#include <hip/hip_runtime.h>
#include <hip/hip_bf16.h>

// Spherical harmonics Y_lm, l=0..3, per point of X[8,512,512,3] (fp32).
// Output per point: 16 rows (l,m ascending) x 2 (re,im) = 32 floats = 8 float4.
// Per-wave register->LDS (XOR-swizzled) transpose done in TWO 32-point passes
// so LDS/block = 16 KB -> 8 blocks/CU (32 waves/CU) for more stores in flight.
// Wave-level lgkmcnt sync only; nontemporal fully-coalesced dwordx4 stores.

typedef float f32x4 __attribute__((ext_vector_type(4)));

__global__ __launch_bounds__(256, 8) void spharm_kernel(
    const float* __restrict__ X, float* __restrict__ out, int n)
{
    __shared__ f32x4 lds[4 * 256];  // 4 waves x 32 points x 8 f32x4 = 16 KB
    const int lane = threadIdx.x & 63;
    const int wave = threadIdx.x >> 6;
    f32x4* w = &lds[wave * 256];
    const int p = blockIdx.x * 256 + threadIdx.x;

    f32x4 v[8];
    if (p < n) {
        const float x = X[3 * p + 0];
        const float y = X[3 * p + 1];
        const float z = X[3 * p + 2];

        const float r  = sqrtf(x * x + y * y + z * z);
        const float ct = z / (r + 1e-12f);
        float st2 = 1.0f - ct * ct;
        st2 = st2 < 0.0f ? 0.0f : (st2 > 1.0f ? 1.0f : st2);
        const float st = sqrtf(st2);

        // cos(phi), sin(phi); atan2(0,0)=0 -> (c,s)=(1,0)
        const float rxy2 = x * x + y * y;
        float c1, s1;
        if (rxy2 > 0.0f) {
            const float inv = rsqrtf(rxy2);
            c1 = x * inv;
            s1 = y * inv;
        } else {
            c1 = 1.0f;
            s1 = 0.0f;
        }
        const float c2 = c1 * c1 - s1 * s1;
        const float s2 = 2.0f * c1 * s1;
        const float c3 = c2 * c1 - s2 * s1;
        const float s3 = s2 * c1 + c2 * s1;

        // Associated Legendre (Condon-Shortley phase)
        const float P10 = ct;
        const float P11 = -st;
        const float P20 = 0.5f * (3.0f * ct * ct - 1.0f);
        const float P21 = -3.0f * ct * st;
        const float P22 = 3.0f * st2;
        const float P30 = 0.5f * ct * (5.0f * ct * ct - 3.0f);
        const float P31 = -1.5f * st * (5.0f * ct * ct - 1.0f);
        const float P32 = 15.0f * ct * st2;
        const float P33 = -15.0f * st * st2;

        const float N00 = 0.28209479177387814f;
        const float N10 = 0.48860251190291990f;
        const float N11 = 0.34549414947133550f;
        const float N20 = 0.63078313050504010f;
        const float N21 = 0.25751613468212640f;
        const float N22 = 0.12875806734106327f;
        const float N30 = 0.74635266518023080f;
        const float N31 = 0.21545345607610050f;
        const float N32 = 0.06813236509555433f;
        const float N33 = 0.02781492157551894f;

        const float q11 = N11 * P11;
        const float q21 = N21 * P21;
        const float q22 = N22 * P22;
        const float q31 = N31 * P31;
        const float q32 = N32 * P32;
        const float q33 = N33 * P33;

        const float re11 = q11 * c1, im11 = q11 * s1;
        const float re21 = q21 * c1, im21 = q21 * s1;
        const float re22 = q22 * c2, im22 = q22 * s2;
        const float re31 = q31 * c1, im31 = q31 * s1;
        const float re32 = q32 * c2, im32 = q32 * s2;
        const float re33 = q33 * c3, im33 = q33 * s3;

        v[0] = (f32x4){N00, 0.0f, -re11, im11};          // l0m0 | l1m-1
        v[1] = (f32x4){N10 * P10, 0.0f, re11, im11};     // l1m0 | l1m1
        v[2] = (f32x4){re22, -im22, -re21, im21};        // l2m-2 | l2m-1
        v[3] = (f32x4){N20 * P20, 0.0f, re21, im21};     // l2m0 | l2m1
        v[4] = (f32x4){re22, im22, -re33, im33};         // l2m2 | l3m-3
        v[5] = (f32x4){re32, -im32, -re31, im31};        // l3m-2 | l3m-1
        v[6] = (f32x4){N30 * P30, 0.0f, re31, im31};     // l3m0 | l3m1
        v[7] = (f32x4){re32, im32, re33, im33};          // l3m2 | l3m3
    } else {
        #pragma unroll
        for (int j = 0; j < 8; ++j) v[j] = (f32x4){0.f, 0.f, 0.f, 0.f};
    }

    f32x4* of4 = reinterpret_cast<f32x4*>(out);
    const size_t lim_f4 = (size_t)n * 8;
    // wave's output base (f32x4 units): first point of this wave * 8
    const size_t wbase = ((size_t)blockIdx.x * 256 + wave * 64) * 8;

    // ---- pass A: points 0..31 of the wave (data in lanes 0..31) ----
    if (lane < 32) {
        #pragma unroll
        for (int j = 0; j < 8; ++j)
            w[lane * 8 + (j ^ (lane & 7))] = v[j];
    }
    asm volatile("s_waitcnt lgkmcnt(0)" ::: "memory");
    #pragma unroll
    for (int j = 0; j < 4; ++j) {
        const int q = j * 64 + lane;   // 0..255
        const int pw = q >> 3;
        const int s = q & 7;
        const f32x4 val = w[pw * 8 + (s ^ (pw & 7))];
        if (wbase + q < lim_f4)
            __builtin_nontemporal_store(val, &of4[wbase + q]);
    }
    // ensure pass-A reads retired before pass-B overwrites the region
    asm volatile("s_waitcnt lgkmcnt(0)" ::: "memory");

    // ---- pass B: points 32..63 of the wave (data in lanes 32..63) ----
    if (lane >= 32) {
        #pragma unroll
        for (int j = 0; j < 8; ++j)
            w[(lane - 32) * 8 + (j ^ (lane & 7))] = v[j];
    }
    asm volatile("s_waitcnt lgkmcnt(0)" ::: "memory");
    #pragma unroll
    for (int j = 0; j < 4; ++j) {
        const int q = j * 64 + lane;   // 0..255
        const int pw = q >> 3;
        const int s = q & 7;
        const f32x4 val = w[pw * 8 + (s ^ (pw & 7))];
        if (wbase + 256 + q < lim_f4)
            __builtin_nontemporal_store(val, &of4[wbase + 256 + q]);
    }
}

extern "C" void kernel_launch(void* const* d_in, const int* in_sizes, int n_in,
                              void* d_out, int out_size, void* d_ws, size_t ws_size,
                              hipStream_t stream) {
    const float* X = (const float*)d_in[0];
    float* out = (float*)d_out;
    const int n = in_sizes[0] / 3;  // number of points
    const int blocks = (n + 255) / 256;
    spharm_kernel<<<blocks, 256, 0, stream>>>(X, out, n);
}